// Round 9
// baseline (306.941 us; speedup 1.0000x reference)
//
#include <hip/hip_runtime.h>

#define B_   32
#define L_   512
#define D_   384
#define M_   (B_*L_)    // 16384 rows
#define KTOT (D_*3)     // 1152 GEMM K
#define LDW  384        // LDS row stride = 768B = 192 banks = 0 mod 32 (swizzle handles spread)
#define BROWS 82        // 80 data rows + 2 guard rows
#define BUFE (BROWS*LDW)

typedef __bf16 bf16x8 __attribute__((ext_vector_type(8)));
typedef float  floatx4 __attribute__((ext_vector_type(4)));

// ---------------- weight repack: chunk-major fragment layout ----------------
// W3[((c*24 + t)*64 + lane)*8 + j] = w[o = t*16 + (lane&15)][kflat = c*32 + (lane>>4)*8 + j]
// kflat = s*384 + i.
__global__ __launch_bounds__(256) void repack4_kernel(const float* __restrict__ wa,
                                                      const float* __restrict__ wb,
                                                      const float* __restrict__ wc,
                                                      const float* __restrict__ wd,
                                                      __bf16* __restrict__ oa,
                                                      __bf16* __restrict__ ob,
                                                      __bf16* __restrict__ oc,
                                                      __bf16* __restrict__ od)
{
    int idx = blockIdx.x * 256 + threadIdx.x;
    if (idx >= D_ * KTOT) return;
    const float* w; __bf16* o_;
    switch (blockIdx.y) {
        case 0:  w = wa; o_ = oa; break;
        case 1:  w = wb; o_ = ob; break;
        case 2:  w = wc; o_ = oc; break;
        default: w = wd; o_ = od; break;
    }
    int j  = idx & 7;
    int l  = (idx >> 3) & 63;
    int ct = idx >> 9;          // c*24 + t
    int c  = ct / 24;
    int t  = ct - c * 24;
    int o  = t * 16 + (l & 15);
    int kflat = c * 32 + (l >> 4) * 8 + j;
    int s  = kflat / D_;
    int i  = kflat - s * D_;
    o_[idx] = (__bf16)w[(o * D_ + i) * 3 + s];
}

// ---------------- fused DurationPredictor: 4 convs + 2 LN + head, ONE kernel ------
// Block = 512 threads (8 waves) owns 64 output rows. Two 82x384 bf16 LDS buffers
// (ping-pong) with XOR-swizzled 16B chunks: element layout
//   addr(beta, col) = beta*384 + (((col>>3) ^ (beta&7))<<3) + (col&7)
// -> staging writes / A-frag b128 reads hit all 32 banks uniformly (conflict-free),
// epilogue scalar writes <=2-way (free). Halo-shrink handles conv SAME padding.
__global__ __launch_bounds__(512, 1) void fused_predictor(
    const float* __restrict__ x,
    const __bf16* __restrict__ w1a, const float* __restrict__ b1a,
    const __bf16* __restrict__ w1b, const float* __restrict__ b1b,
    const float* __restrict__ g1,  const float* __restrict__ e1,
    const __bf16* __restrict__ w2a, const float* __restrict__ b2a,
    const __bf16* __restrict__ w2b, const float* __restrict__ b2b,
    const float* __restrict__ g2,  const float* __restrict__ e2,
    const float* __restrict__ lw,  const float* __restrict__ lb,
    float* __restrict__ out_dur)
{
    extern __shared__ char smem_raw[];
    __bf16* bufA = (__bf16*)smem_raw;
    __bf16* bufB = bufA + BUFE;
    float*  red1 = (float*)(bufB + BUFE);    // [BROWS][8]
    float*  red2 = red1 + BROWS * 8;         // [BROWS][8]
    float*  minv = red2 + BROWS * 8;         // [BROWS][2]

    const int m0 = blockIdx.x * 64;
    const int l0 = m0 & 511;
    const int b0 = m0 - l0;

    const int tid  = threadIdx.x;
    const int wave = tid >> 6;        // 0..7; owns cols [wave*48, wave*48+48)
    const int lane = tid & 63;
    const int quad = lane >> 4;
    const int lx   = lane & 15;

    bf16x8 kz;
#pragma unroll
    for (int z = 0; z < 8; z++) kz[z] = (__bf16)0.f;

    // ---- stage x -> bufA (fp32->bf16, zero outside seq); zero bufB guards ----
    for (int c = tid; c < BROWS * 48; c += 512) {
        int beta = c / 48, q = c - beta * 48;
        int l = l0 + beta - 9;
        bf16x8 v = kz;
        if ((unsigned)l < (unsigned)L_) {
            const float* xr = x + (size_t)(b0 + l) * D_ + q * 8;
            const float4 f0 = *(const float4*)xr;
            const float4 f1 = *(const float4*)(xr + 4);
            v[0] = (__bf16)f0.x; v[1] = (__bf16)f0.y; v[2] = (__bf16)f0.z; v[3] = (__bf16)f0.w;
            v[4] = (__bf16)f1.x; v[5] = (__bf16)f1.y; v[6] = (__bf16)f1.z; v[7] = (__bf16)f1.w;
        }
        *(bf16x8*)(&bufA[beta * LDW + ((q ^ (beta & 7)) << 3)]) = v;
    }
    for (int c = tid; c < 2 * 48; c += 512) {
        int beta = (c < 48) ? 0 : 81, q = c % 48;
        *(bf16x8*)(&bufB[beta * LDW + (q << 3)]) = kz;   // whole row zero; swizzle moot
    }
    __syncthreads();

    const int t0  = wave * 3;                 // n-tiles of this wave
    const int col0 = wave * 48 + lx;          // col for ni: col0 + ni*16

    floatx4 acc[5][3];
    bf16x8  bg[3][3];

    for (int st = 0; st < 4; st++) {
        const __bf16* bin  = (st & 1) ? bufB : bufA;
        __bf16*       bout = (st & 1) ? bufA : bufB;
        const __bf16* Wp = (st == 0) ? w1a : (st == 1) ? w1b : (st == 2) ? w2a : w2b;
        const float*  bp = (st == 0) ? b1a : (st == 1) ? b1b : (st == 2) ? b2a : b2b;

#pragma unroll
        for (int mt = 0; mt < 5; mt++)
#pragma unroll
            for (int ni = 0; ni < 3; ni++)
#pragma unroll
                for (int r = 0; r < 4; r++) acc[mt][ni][r] = 0.f;

        const char* pb0 = (const char*)Wp + ((size_t)t0 * 64 + lane) * 16;
        auto loadB = [&](int buf, int n) {
            int it = n / 3, s = n - it * 3;
            const char* p = pb0 + (size_t)(s * 12 + it) * 24576;
#pragma unroll
            for (int ni = 0; ni < 3; ni++)
                bg[buf][ni] = *(const bf16x8*)(p + ni * 1024);
        };
        loadB(0, 0); loadB(1, 1);

#pragma unroll
        for (int n = 0; n < 36; n++) {
            const int it = n / 3, s = n - it * 3;
            if (n + 2 < 36) loadB((n + 2) % 3, n + 2);
            const int key = (lx + s) & 7;
            bf16x8 af[5];
#pragma unroll
            for (int mt = 0; mt < 5; mt++) {
                const int beta = mt * 16 + s + lx;
                af[mt] = *(const bf16x8*)(&bin[beta * LDW + (((it * 4 + quad) ^ key) << 3)]);
            }
#pragma unroll
            for (int mt = 0; mt < 5; mt++)
#pragma unroll
                for (int ni = 0; ni < 3; ni++)
                    acc[mt][ni] = __builtin_amdgcn_mfma_f32_16x16x32_bf16(af[mt], bg[n % 3][ni], acc[mt][ni], 0, 0, 0);
        }

        // ---- epilogue: bias + relu (in place) ----
        float bv[3];
#pragma unroll
        for (int ni = 0; ni < 3; ni++) bv[ni] = bp[col0 + ni * 16];
#pragma unroll
        for (int mt = 0; mt < 5; mt++)
#pragma unroll
            for (int ni = 0; ni < 3; ni++)
#pragma unroll
                for (int r = 0; r < 4; r++) {
                    float vv = acc[mt][ni][r] + bv[ni];
                    acc[mt][ni][r] = vv > 0.f ? vv : 0.f;
                }

        if (st == 1 || st == 3) {
            // ---- LayerNorm: row stats via lx-shuffle + cross-wave LDS reduce ----
#pragma unroll
            for (int mt = 0; mt < 5; mt++)
#pragma unroll
                for (int r = 0; r < 4; r++) {
                    float s1 = acc[mt][0][r] + acc[mt][1][r] + acc[mt][2][r];
                    float s2 = acc[mt][0][r] * acc[mt][0][r] + acc[mt][1][r] * acc[mt][1][r]
                             + acc[mt][2][r] * acc[mt][2][r];
#pragma unroll
                    for (int d = 1; d < 16; d <<= 1) {
                        s1 += __shfl_xor(s1, d);
                        s2 += __shfl_xor(s2, d);
                    }
                    if (lx == 0) {
                        int beta = mt * 16 + quad * 4 + r + 1;
                        red1[beta * 8 + wave] = s1;
                        red2[beta * 8 + wave] = s2;
                    }
                }
            __syncthreads();
            if (tid < BROWS) {
                float s1 = 0.f, s2 = 0.f;
#pragma unroll
                for (int w = 0; w < 8; w++) { s1 += red1[tid * 8 + w]; s2 += red2[tid * 8 + w]; }
                float mean = s1 * (1.f / D_);
                float var  = s2 * (1.f / D_) - mean * mean;
                minv[tid * 2]     = mean;
                minv[tid * 2 + 1] = rsqrtf(var + 1e-5f);
            }
            __syncthreads();
            const float* gp = (st == 1) ? g1 : g2;
            const float* ep = (st == 1) ? e1 : e2;
            float gv[3], ev[3];
#pragma unroll
            for (int ni = 0; ni < 3; ni++) { gv[ni] = gp[col0 + ni * 16]; ev[ni] = ep[col0 + ni * 16]; }
#pragma unroll
            for (int mt = 0; mt < 5; mt++)
#pragma unroll
                for (int r = 0; r < 4; r++) {
                    int beta = mt * 16 + quad * 4 + r + 1;
                    float mean = minv[beta * 2], inv = minv[beta * 2 + 1];
#pragma unroll
                    for (int ni = 0; ni < 3; ni++)
                        acc[mt][ni][r] = (acc[mt][ni][r] - mean) * inv * gv[ni] + ev[ni];
                }
            if (st == 1) {
#pragma unroll
                for (int mt = 0; mt < 5; mt++)
#pragma unroll
                    for (int r = 0; r < 4; r++) {
                        int beta = mt * 16 + quad * 4 + r + 1;
                        int key = beta & 7;
                        bool ok = (unsigned)(l0 + beta - 9) < (unsigned)L_;
#pragma unroll
                        for (int ni = 0; ni < 3; ni++) {
                            int col = col0 + ni * 16;
                            bout[beta * LDW + ((((col >> 3) ^ key) << 3) | (col & 7))] =
                                (__bf16)(ok ? acc[mt][ni][r] : 0.f);
                        }
                    }
            } else {
                // ---- head: dot with lin_w, cross-wave reduce, store dur_preds ----
                float lwv[3];
#pragma unroll
                for (int ni = 0; ni < 3; ni++) lwv[ni] = lw[col0 + ni * 16];
#pragma unroll
                for (int mt = 0; mt < 5; mt++)
#pragma unroll
                    for (int r = 0; r < 4; r++) {
                        float p = acc[mt][0][r] * lwv[0] + acc[mt][1][r] * lwv[1] + acc[mt][2][r] * lwv[2];
#pragma unroll
                        for (int d = 1; d < 16; d <<= 1) p += __shfl_xor(p, d);
                        if (lx == 0) {
                            int beta = mt * 16 + quad * 4 + r + 1;
                            red1[beta * 8 + wave] = p;
                        }
                    }
                __syncthreads();
                if (tid < 64) {
                    int beta = tid + 9;
                    float sacc = lb[0];
#pragma unroll
                    for (int w = 0; w < 8; w++) sacc += red1[beta * 8 + w];
                    out_dur[m0 + tid] = sacc;
                }
            }
        } else {
            // ---- plain write (conv1a / conv2a outputs) ----
#pragma unroll
            for (int mt = 0; mt < 5; mt++)
#pragma unroll
                for (int r = 0; r < 4; r++) {
                    int beta = mt * 16 + quad * 4 + r + 1;
                    int key = beta & 7;
                    bool ok = (unsigned)(l0 + beta - 9) < (unsigned)L_;
#pragma unroll
                    for (int ni = 0; ni < 3; ni++) {
                        int col = col0 + ni * 16;
                        bout[beta * LDW + ((((col >> 3) ^ key) << 3) | (col & 7))] =
                            (__bf16)(ok ? acc[mt][ni][r] : 0.f);
                    }
                }
        }
        __syncthreads();
    }
}

// ---------------- cumsum of durations, wave per batch ----------------
__global__ __launch_bounds__(64) void cum_kernel(const int* __restrict__ dur,
                                                 int* __restrict__ cum)
{
    int b = blockIdx.x, lane = threadIdx.x;
    const int* db = dur + b * L_;
    int v[8], s = 0;
#pragma unroll
    for (int i = 0; i < 8; i++) { v[i] = db[lane * 8 + i]; s += v[i]; }
    int ex = s;
#pragma unroll
    for (int off = 1; off < 64; off <<= 1) {
        int n = __shfl_up(ex, off);
        if (lane >= off) ex += n;
    }
    ex -= s;
    int c = ex;
    int* cb = cum + b * L_;
#pragma unroll
    for (int i = 0; i < 8; i++) { c += v[i]; cb[lane * 8 + i] = c; }
}

// ---------------- LR pass 1: frame -> source row index (or -1) ----------------
__global__ __launch_bounds__(256) void idx_kernel(const int* __restrict__ cum,
                                                  int* __restrict__ idx, int T, int nf)
{
    int f = blockIdx.x * 256 + threadIdx.x;
    if (f >= nf) return;
    int b = f / T;
    int t = f - b * T;
    const int* cb = cum + b * L_;
    int v = -1;
    if (t < cb[L_ - 1]) {
        int lo = 0, hi = L_;
        while (lo < hi) { int mid = (lo + hi) >> 1; if (cb[mid] > t) hi = mid; else lo = mid + 1; }
        v = b * L_ + lo;
    }
    idx[f] = v;
}

// ---------------- LR pass 2: pure coalesced copy, thread per float4 chunk ----------
__global__ __launch_bounds__(256) void copy_kernel(const float* __restrict__ x,
                                                   const int* __restrict__ idx,
                                                   float* __restrict__ out, int nchunks)
{
    int gid = blockIdx.x * 256 + threadIdx.x;
    if (gid >= nchunks) return;
    int f = gid / 96;                 // const-div -> mulhi
    int c = gid - f * 96;
    int src = idx[f];
    float4 v = make_float4(0.f, 0.f, 0.f, 0.f);
    if (src >= 0) v = *(const float4*)(x + (size_t)src * D_ + c * 4);
    *(float4*)(out + (size_t)gid * 4) = v;
}

extern "C" void kernel_launch(void* const* d_in, const int* in_sizes, int n_in,
                              void* d_out, int out_size, void* d_ws, size_t ws_size,
                              hipStream_t stream) {
    const float* x       = (const float*)d_in[0];
    const int*   dur     = (const int*)d_in[1];
    const float* c1a_w   = (const float*)d_in[2];
    const float* c1a_b   = (const float*)d_in[3];
    const float* c1b_w   = (const float*)d_in[4];
    const float* c1b_b   = (const float*)d_in[5];
    const float* ln1_g   = (const float*)d_in[6];
    const float* ln1_b   = (const float*)d_in[7];
    const float* c2a_w   = (const float*)d_in[8];
    const float* c2a_b   = (const float*)d_in[9];
    const float* c2b_w   = (const float*)d_in[10];
    const float* c2b_b   = (const float*)d_in[11];
    const float* ln2_g   = (const float*)d_in[12];
    const float* ln2_b   = (const float*)d_in[13];
    const float* lin_w   = (const float*)d_in[14];
    const float* lin_b   = (const float*)d_in[15];

    const int T = (out_size - B_ * L_) / (B_ * D_);
    float* out_gather = (float*)d_out;
    float* out_dur    = (float*)d_out + (size_t)B_ * T * D_;

    // workspace: 4 repacked weights + cumsum + frame index
    char* p = (char*)d_ws;
    __bf16* w1a = (__bf16*)p; p += (size_t)D_ * KTOT * 2;
    __bf16* w1b = (__bf16*)p; p += (size_t)D_ * KTOT * 2;
    __bf16* w2a = (__bf16*)p; p += (size_t)D_ * KTOT * 2;
    __bf16* w2b = (__bf16*)p; p += (size_t)D_ * KTOT * 2;
    int* cum = (int*)p; p += (size_t)B_ * L_ * 4;
    int* idx = (int*)p; p += (size_t)B_ * T * 4;

    // LR path
    const int nf = B_ * T;
    cum_kernel<<<B_, 64, 0, stream>>>(dur, cum);
    idx_kernel<<<(nf + 255) / 256, 256, 0, stream>>>(cum, idx, T, nf);
    const int nchunks = nf * 96;
    copy_kernel<<<(nchunks + 255) / 256, 256, 0, stream>>>(x, idx, out_gather, nchunks);

    // predictor chain: repack -> one fused kernel
    dim3 rpgrid((D_ * KTOT + 255) / 256, 4);
    repack4_kernel<<<rpgrid, 256, 0, stream>>>(c1a_w, c1b_w, c2a_w, c2b_w, w1a, w1b, w2a, w2b);

    const size_t smem = (size_t)2 * BUFE * 2 + (BROWS * 8 * 2 + BROWS * 2) * 4;
    hipFuncSetAttribute((const void*)fused_predictor,
                        hipFuncAttributeMaxDynamicSharedMemorySize, (int)smem);
    fused_predictor<<<256, 512, smem, stream>>>(
        x, w1a, c1a_b, w1b, c1b_b, ln1_g, ln1_b,
        w2a, c2a_b, w2b, c2b_b, ln2_g, ln2_b,
        lin_w, lin_b, out_dur);
}